// Round 14
// baseline (637.620 us; speedup 1.0000x reference)
//
#include <hip/hip_runtime.h>

// Problem constants (fixed by the reference)
#define N2 2048
#define NNZ 32768
#define LK 22          // FROZEN: absmax 0.0234 of 0.037 threshold (3 of ~4.7 bf16 ulps)
#define NBLK 512       // 512 blocks = 2/CU; all phases in one cooperative kernel
#define BINCAP 64      // slots per row bin (Poisson(16) tail ~1e-15)

typedef __attribute__((ext_vector_type(8))) _Float16 half8;
typedef __attribute__((ext_vector_type(4))) float f32x4;

#define AGENT __HIP_MEMORY_SCOPE_AGENT
#define AS1C(p) ((const __attribute__((address_space(1))) unsigned int*)(p))
#define AS3(p)  ((__attribute__((address_space(3))) unsigned int*)(p))

__device__ __forceinline__ unsigned short f2h(float f) {
  _Float16 h = (_Float16)f;                   // fp16 RNE; |W| < ~5.5, in range
  return *(unsigned short*)&h;
}

// ---- phase barrier with coherence (R3 mechanism, once per PHASE not per iter) ----
// release: __threadfence (wbl2 -> IC flush of this XCD's dirty lines) before
// flag publish; acquire: __threadfence (inv) after all flags observed. All
// phase data then uses normal cached loads/stores. Poll window (v-ph)<=1:
// poison 0xAA and stale prior-run flags fail it; every block rewrites its own
// flag each phase => self-correcting from any initial content; skew <= 1 phase
// (a block can't pass barrier ph+1 until all wrote ph+1). [R4-proven poll shape]
__device__ __forceinline__ void phase_bar(unsigned* flags, unsigned ph) {
  __syncthreads();
  if (threadIdx.x == 0) {
    __threadfence();
    __hip_atomic_store(&flags[blockIdx.x], ph, __ATOMIC_RELAXED, AGENT);
  }
  for (;;) {
    unsigned v0 = __hip_atomic_load(&flags[threadIdx.x], __ATOMIC_RELAXED, AGENT);
    unsigned v1 = __hip_atomic_load(&flags[threadIdx.x + 256], __ATOMIC_RELAXED, AGENT);
    bool ok = ((v0 - ph) <= 1u) && ((v1 - ph) <= 1u);
    if (__syncthreads_and((int)ok)) break;
  }
  if (threadIdx.x == 0) __threadfence();
  __syncthreads();
}

// ---- deterministic block-wide sum: identical bitwise result in every block ----
__device__ __forceinline__ float block_sum(float v, float* red) {
#pragma unroll
  for (int off = 32; off; off >>= 1) v += __shfl_down(v, off);
  if ((threadIdx.x & 63) == 0) red[threadIdx.x >> 6] = v;
  __syncthreads();
  float r = red[0] + red[1] + red[2] + red[3];
  __syncthreads();
  return r;
}

// ============ THE WHOLE PIPELINE: one cooperative kernel, 7 phases ============
// RULE 1 (R1/R6): cross-block data inside an unfenced loop moves via agent-
// scope (sc1) atomics only (lanczos Z). Phase-level exchange uses normal
// memory + the fence-carrying phase_bar.
// RULE 2 (R1/R6/R8, 3/3): beta^2 = ||z - alpha v||^2 DIRECT form only —
// the ||z||^2 - alpha^2 identity feeds normalization error back with gain
// alpha^2/beta^2 (~10x/iter) and collapses lambda_min.
__global__ __launch_bounds__(256) void mega_kernel(
    const float* __restrict__ W, const float* __restrict__ pred,
    const float* __restrict__ scal, const int* __restrict__ rows,
    const int* __restrict__ cols,
    unsigned short* __restrict__ Hf, float* __restrict__ A,
    float* __restrict__ F, float* __restrict__ Ft,
    unsigned* __restrict__ cnt, int* __restrict__ bcol,
    float* __restrict__ bval,
    unsigned long long* __restrict__ Z0, unsigned long long* __restrict__ Z1,
    unsigned* __restrict__ flags, float* __restrict__ out) {
  const int tid = threadIdx.x, b = blockIdx.x;
  const int wave = tid >> 6, lane = tid & 63;
  __shared__ unsigned short Xs[64 * 32];
  __shared__ unsigned short Ys[128 * 32];
  __shared__ float T2[32][33];
  __shared__ __align__(16) float VA[2048];
  __shared__ __align__(16) float VB[2048];
  __shared__ float red[4];
  __shared__ float al[LK + 2], b2[LK + 2];
  __shared__ float bnds[2], res[2];

  // ---- P0: W -> fp16, zero cnt ----
  {
    int g = b * 256 + tid;
    if (g < 2048) cnt[g] = 0;
#pragma unroll
    for (int c = 0; c < 8; ++c) {
      int i4 = c * 131072 + g;
      float4 w = ((const float4*)W)[i4];
      ushort4 h;
      h.x = f2h(w.x); h.y = f2h(w.y); h.z = f2h(w.z); h.w = f2h(w.w);
      ((ushort4*)Hf)[i4] = h;
    }
  }
  phase_bar(flags, 1);

  // ---- P1: A = Hf*Hf^T/N + I  (64x128 tile per block; exactly symmetric
  //      by construction (W+E)(W+E)^T; eig shift <= 2|W||E|/N ~ 0.0024) ----
  {
    const int bi = b >> 4, bj = b & 15;
    const int row0 = bi * 64, col0 = bj * 128;
    const int m0 = (wave & 1) * 32, n0 = (wave >> 1) * 64;
    f32x4 acc[2][4];
#pragma unroll
    for (int a = 0; a < 2; ++a)
#pragma unroll
      for (int q = 0; q < 4; ++q) acc[a][q] = (f32x4){0.f, 0.f, 0.f, 0.f};
    const int mrow = lane & 15, kseg = (lane >> 4) * 8;
    const int srowX = wave * 16 + (lane >> 2);
    const int srowY = wave * 32 + (lane >> 2);
    const int scol = (lane & 3) * 8;
    for (int k0 = 0; k0 < 2048; k0 += 32) {
      __syncthreads();
      __builtin_amdgcn_global_load_lds(
          AS1C(Hf + (size_t)(row0 + srowX) * 2048 + k0 + scol),
          AS3(Xs + (wave * 16) * 32), 16, 0, 0);
#pragma unroll
      for (int q = 0; q < 2; ++q) {
        __builtin_amdgcn_global_load_lds(
            AS1C(Hf + (size_t)(col0 + srowY + q * 16) * 2048 + k0 + scol),
            AS3(Ys + (wave * 32 + q * 16) * 32), 16, 0, 0);
      }
      __syncthreads();
      half8 af[2], bf[4];
#pragma unroll
      for (int t = 0; t < 2; ++t)
        af[t] = *(const half8*)(Xs + (m0 + t * 16 + mrow) * 32 + kseg);
#pragma unroll
      for (int t = 0; t < 4; ++t)
        bf[t] = *(const half8*)(Ys + (n0 + t * 16 + mrow) * 32 + kseg);
#pragma unroll
      for (int mt = 0; mt < 2; ++mt)
#pragma unroll
        for (int nt = 0; nt < 4; ++nt)
          acc[mt][nt] = __builtin_amdgcn_mfma_f32_16x16x32_f16(af[mt], bf[nt], acc[mt][nt], 0, 0, 0);
    }
    // C/D layout: col = lane&15, row = (lane>>4)*4 + reg [m89, dtype-indep]
    const int crow = (lane >> 4) * 4, ccol = lane & 15;
    const float invn = 1.0f / 2048.0f;
#pragma unroll
    for (int mt = 0; mt < 2; ++mt)
#pragma unroll
      for (int nt = 0; nt < 4; ++nt) {
        const int gi0 = row0 + m0 + mt * 16 + crow;
        const int gj = col0 + n0 + nt * 16 + ccol;
        size_t base = (size_t)gi0 * 2048 + gj;
#pragma unroll
        for (int r = 0; r < 4; ++r)
          A[base + (size_t)r * 2048] = acc[mt][nt][r] * invn + ((gi0 + r == gj) ? 1.0f : 0.0f);
      }
  }
  phase_bar(flags, 2);

  // ---- P2: fill fixed-stride bins (atomic slot alloc; 64 entries/block) ----
  if (tid < 64) {
    int k = b * 64 + tid;
    int r = rows[k];
    unsigned pos = atomicAdd(&cnt[r], 1u);
    if (pos < BINCAP) {
      bcol[r * BINCAP + pos] = cols[k];
      bval[r * BINCAP + pos] = pred[k] * scal[k];
    }
  }
  phase_bar(flags, 3);

  // ---- P3: F[r,:] = sum_e val_e * A[col_e,:]  (4 rows per block) ----
#pragma unroll
  for (int rr = 0; rr < 4; ++rr) {
    const int r = b * 4 + rr;
    float4 a0 = {0.f, 0.f, 0.f, 0.f}, a1 = {0.f, 0.f, 0.f, 0.f};
    const unsigned ne = min(cnt[r], (unsigned)BINCAP);
    for (unsigned e = 0; e < ne; ++e) {
      const float v = bval[r * BINCAP + e];
      const float4* Ar = (const float4*)(A + (size_t)bcol[r * BINCAP + e] * 2048);
      float4 x0 = Ar[tid], x1 = Ar[tid + 256];
      a0.x += v * x0.x; a0.y += v * x0.y; a0.z += v * x0.z; a0.w += v * x0.w;
      a1.x += v * x1.x; a1.y += v * x1.y; a1.z += v * x1.z; a1.w += v * x1.w;
    }
    float4* Fr = (float4*)(F + (size_t)r * 2048);
    Fr[tid] = a0;
    Fr[tid + 256] = a1;
  }
  phase_bar(flags, 4);

  // ---- P4: M(=A) += F + F^T;  Ft = F^T   (8 32x32 tile-pairs per block) ----
#pragma unroll
  for (int t8 = 0; t8 < 8; ++t8) {
    const int tile = b * 8 + t8;
    const int bi = tile & 63, bj = tile >> 6;
    const int c = tid & 31, r0 = tid >> 5;
#pragma unroll
    for (int it = 0; it < 4; ++it) {
      int r = r0 + it * 8;
      T2[r][c] = F[(size_t)(bj * 32 + r) * 2048 + bi * 32 + c];
    }
    __syncthreads();
#pragma unroll
    for (int it = 0; it < 4; ++it) {
      int r = r0 + it * 8;
      size_t idx = (size_t)(bi * 32 + r) * 2048 + bj * 32 + c;
      float ft = T2[c][r];
      A[idx] += F[idx] + ft;
      Ft[idx] = ft;
    }
    __syncthreads();
  }
  phase_bar(flags, 5);

  // ---- P5: M(=A)[r,:] += sum_e val_e * Ft[col_e,:]  (4 rows per block) ----
#pragma unroll
  for (int rr = 0; rr < 4; ++rr) {
    const int r = b * 4 + rr;
    float4 a0 = {0.f, 0.f, 0.f, 0.f}, a1 = {0.f, 0.f, 0.f, 0.f};
    const unsigned ne = min(cnt[r], (unsigned)BINCAP);
    for (unsigned e = 0; e < ne; ++e) {
      const float v = bval[r * BINCAP + e];
      const float4* Fr = (const float4*)(Ft + (size_t)bcol[r * BINCAP + e] * 2048);
      float4 x0 = Fr[tid], x1 = Fr[tid + 256];
      a0.x += v * x0.x; a0.y += v * x0.y; a0.z += v * x0.z; a0.w += v * x0.w;
      a1.x += v * x1.x; a1.y += v * x1.y; a1.z += v * x1.z; a1.w += v * x1.w;
    }
    float4* Mr = (float4*)(A + (size_t)r * 2048);
    float4 m0 = Mr[tid], m1 = Mr[tid + 256];
    m0.x += a0.x; m0.y += a0.y; m0.z += a0.z; m0.w += a0.w;
    m1.x += a1.x; m1.y += a1.y; m1.z += a1.z; m1.w += a1.w;
    Mr[tid] = m0;
    Mr[tid + 256] = m1;
  }
  phase_bar(flags, 6);   // acquire-inv here; M then L2-caches across iterations

  // ---- P6: Lanczos (epoch-tagged Z, fence-free inner loop) + Sturm ----
  {
    const float* M = A;
    float pv[8];
    float part = 0.f;
#pragma unroll
    for (int t = 0; t < 8; ++t) {
      int i = t * 256 + tid;
      unsigned u = (unsigned)i * 2654435761u;
      u ^= u >> 16; u *= 2246822519u; u ^= u >> 13;
      float rv = (float)(u >> 8) * (2.f / 16777216.f) - 1.f;
      pv[t] = rv;
      part += rv * rv;
    }
    float nrm = block_sum(part, red);
    float innm = rsqrtf(nrm);
#pragma unroll
    for (int t = 0; t < 8; ++t) {
      int i = t * 256 + tid;
      VA[i] = pv[t] * innm;
      VB[i] = 0.f;
    }
    __syncthreads();

    float* Vcur = VA;
    float* Vprev = VB;
    float beta_prev = 0.f;

    for (int j = 1; j <= LK; ++j) {
      unsigned long long* Z = (j & 1) ? Z0 : Z1;
      // this block's 4 rows (1/wave) of z = M v_j - beta_{j-1} v_{j-1}
      {
        const int r = b * 4 + wave;
        const float4* Mr = (const float4*)(M + (size_t)r * 2048);
        float s = 0.f;
#pragma unroll
        for (int t = 0; t < 8; ++t) {
          int idx = t * 64 + lane;
          float4 m4 = Mr[idx];
          float4 v4 = ((const float4*)Vcur)[idx];
          s += m4.x * v4.x + m4.y * v4.y + m4.z * v4.z + m4.w * v4.w;
        }
#pragma unroll
        for (int off = 32; off; off >>= 1) s += __shfl_down(s, off);
        if (lane == 0) {
          float zv = s - beta_prev * Vprev[r];
          unsigned long long pk = ((unsigned long long)(unsigned)j << 32) |
                                  (unsigned long long)(unsigned)__float_as_uint(zv);
          __hip_atomic_store(&Z[r], pk, __ATOMIC_RELAXED, AGENT);
        }
      }
      // poll own 8 Z words until epoch == j (exact match; poison/stale safe)
      unsigned long long w8[8];
      for (;;) {
        bool ok = true;
#pragma unroll
        for (int t = 0; t < 8; ++t) {
          w8[t] = __hip_atomic_load(&Z[t * 256 + tid], __ATOMIC_RELAXED, AGENT);
          ok &= ((unsigned)(w8[t] >> 32) == (unsigned)j);
        }
        if (ok) break;
      }
      // redundant deterministic scalars, DIRECT beta form (Rule 2)
      float za[8], va[8];
      float pa = 0.f;
#pragma unroll
      for (int t = 0; t < 8; ++t) {
        za[t] = __uint_as_float((unsigned)w8[t]);
        va[t] = Vcur[t * 256 + tid];
        pa += za[t] * va[t];
      }
      float alpha = block_sum(pa, red);
      float pb = 0.f;
#pragma unroll
      for (int t = 0; t < 8; ++t) {
        float rsd = za[t] - alpha * va[t];
        pb += rsd * rsd;
      }
      float beta2 = block_sum(pb, red);
      float beta = sqrtf(fmaxf(beta2, 1e-30f));
      float invb = 1.f / beta;
      if (tid == 0) { al[j] = alpha; b2[j] = beta2; }
#pragma unroll
      for (int t = 0; t < 8; ++t) {
        int i = t * 256 + tid;
        Vprev[i] = (za[t] - alpha * va[t]) * invb;
      }
      float* tmp = Vprev; Vprev = Vcur; Vcur = tmp;
      beta_prev = beta;
      __syncthreads();
    }

    // extreme eigenvalues of T via Sturm bisection (block 0)
    if (b == 0) {
      if (tid == 0) {
        float lo = 1e30f, hi = -1e30f;
        for (int i = 1; i <= LK; ++i) {
          float bl = (i > 1) ? sqrtf(b2[i - 1]) : 0.f;
          float br = (i < LK) ? sqrtf(b2[i]) : 0.f;
          lo = fminf(lo, al[i] - bl - br);
          hi = fmaxf(hi, al[i] + bl + br);
        }
        bnds[0] = lo; bnds[1] = hi;
      }
      __syncthreads();
      if (wave < 2) {               // wave 0 -> lambda_min, wave 1 -> lambda_max
        const int tcount = (wave == 0) ? 1 : LK;
        float lo = bnds[0], hi = bnds[1];
        for (int round = 0; round < 4; ++round) {
          float x = lo + (hi - lo) * (float)(lane + 1) * (1.f / 65.f);
          int cn = 0;
          float d = al[1] - x;
          if (fabsf(d) < 1e-25f) d = -1e-25f;
          if (d < 0.f) cn++;
          for (int i = 2; i <= LK; ++i) {
            d = (al[i] - x) - b2[i - 1] / d;
            if (fabsf(d) < 1e-25f) d = -1e-25f;
            if (d < 0.f) cn++;
          }
          bool ab = (cn >= tcount);
          float cand_hi = ab ? x : hi;
          float cand_lo = ab ? lo : x;
#pragma unroll
          for (int off = 32; off; off >>= 1) {
            cand_hi = fminf(cand_hi, __shfl_down(cand_hi, off));
            cand_lo = fmaxf(cand_lo, __shfl_down(cand_lo, off));
          }
          cand_hi = __shfl(cand_hi, 0);
          cand_lo = __shfl(cand_lo, 0);
          hi = cand_hi;
          lo = fminf(cand_lo, hi);
        }
        if (lane == 0) res[wave] = 0.5f * (lo + hi);
      }
      __syncthreads();
      if (tid == 0) {
        float lmin = fmaxf(res[0], 1e-12f);
        float lmax = fmaxf(res[1], 1e-12f);
        out[0] = logf(lmax) - logf(lmin);
      }
    }
  }
}

extern "C" void kernel_launch(void* const* d_in, const int* in_sizes, int n_in,
                              void* d_out, int out_size, void* d_ws, size_t ws_size,
                              hipStream_t stream) {
  const float* pred = (const float*)d_in[0];
  const float* scal = (const float*)d_in[1];
  const float* W    = (const float*)d_in[2];
  const int*   rows = (const int*)d_in[3];
  const int*   cols = (const int*)d_in[4];
  float* out = (float*)d_out;

  // workspace layout (peak ~49.1 MB):
  //  [0,16MB)  : Hf fp16 (8MB) during P1, then Ft
  //  [16,32MB) : F
  //  [32,48MB) : A, updated in place into M
  //  [48MB,..) : cnt, bins, epoch-Z ping-pong, phase flags
  char* ws = (char*)d_ws;
  const size_t MB = 1024 * 1024;
  unsigned short* Hf = (unsigned short*)(ws);
  float* Ft = (float*)(ws);             // reuses Hf (dead after P1)
  float* F  = (float*)(ws + 16 * MB);
  float* A  = (float*)(ws + 32 * MB);
  char* ctrl = ws + 48 * MB;
  unsigned* cnt  = (unsigned*)(ctrl);                    //  8 KB (zeroed in P0)
  int*      bcol = (int*)(ctrl + 8192);                  //  512 KB
  float*    bval = (float*)(ctrl + 8192 + 524288);       //  512 KB
  unsigned long long* Z0 = (unsigned long long*)(ctrl + 8192 + 1048576);         // 16 KB
  unsigned long long* Z1 = (unsigned long long*)(ctrl + 8192 + 1048576 + 16384); // 16 KB
  unsigned* flags = (unsigned*)(ctrl + 8192 + 1048576 + 32768);                  //  2 KB

  void* args[] = {(void*)&W,  (void*)&pred, (void*)&scal, (void*)&rows,
                  (void*)&cols, (void*)&Hf, (void*)&A,    (void*)&F,
                  (void*)&Ft, (void*)&cnt,  (void*)&bcol, (void*)&bval,
                  (void*)&Z0, (void*)&Z1,   (void*)&flags, (void*)&out};
  hipLaunchCooperativeKernel((void*)mega_kernel, dim3(NBLK), dim3(256), args, 0, stream);
}

// Round 15
// 323.210 us; speedup vs baseline: 1.9728x; 1.9728x over previous
//
#include <hip/hip_runtime.h>

// Problem constants (fixed by the reference)
#define N2 2048
#define NNZ 32768
#define LK 22          // FROZEN: absmax 0.0234 of 0.037 threshold (3 of ~4.7 bf16 ulps)
#define NB 256         // lanczos grid blocks = 1/CU -> co-resident by construction
#define BINCAP 64      // slots per row bin (Poisson(16) tail ~1e-15)

typedef __attribute__((ext_vector_type(8))) _Float16 half8;
typedef __attribute__((ext_vector_type(4))) float f32x4;

#define AGENT __HIP_MEMORY_SCOPE_AGENT
#define AS1C(p) ((const __attribute__((address_space(1))) unsigned int*)(p))
#define AS3(p)  ((__attribute__((address_space(3))) unsigned int*)(p))

__device__ __forceinline__ unsigned short f2h(float f) {
  _Float16 h = (_Float16)f;                   // fp16 RNE; |W| < ~5.5, in range
  return *(unsigned short*)&h;
}

// ---- 1. W (fp32) -> fp16  (+ zero cnt for the binning pass) ----
__global__ __launch_bounds__(256) void convert_kernel(const float* __restrict__ W,
                                                      unsigned short* __restrict__ Hf,
                                                      unsigned* __restrict__ cnt) {
  if (blockIdx.x < 8) cnt[blockIdx.x * 256 + threadIdx.x] = 0;
  int i4 = blockIdx.x * 256 + threadIdx.x;          // grid 4096 -> 1048576 float4s
  float4 w = ((const float4*)W)[i4];
  ushort4 h;
  h.x = f2h(w.x); h.y = f2h(w.y); h.z = f2h(w.z); h.w = f2h(w.w);
  ((ushort4*)Hf)[i4] = h;
}

// ---- 2. A = Hf*Hf^T/N + I  (single fp16 pass; exactly symmetric by construction:
//         (W+E)(W+E)^T — no symmetrization pass needed; eig shift <= 2|W||E|/N ~ 0.0024)
//         64x128 tile, 512 blocks = 2/CU at N=2048; epilogue applies /N + I ----
__global__ __launch_bounds__(256) void gemm_f16_kernel(const unsigned short* __restrict__ Hf,
                                                       float* __restrict__ A) {
  __shared__ unsigned short Xs[64 * 32];
  __shared__ unsigned short Ys[128 * 32];
  const int tid = threadIdx.x;
  const int wave = tid >> 6, lane = tid & 63;
  const int bi = blockIdx.x >> 4, bj = blockIdx.x & 15;   // 32 x 16 tiles
  const int row0 = bi * 64, col0 = bj * 128;
  const int m0 = (wave & 1) * 32, n0 = (wave >> 1) * 64;
  f32x4 acc[2][4];
#pragma unroll
  for (int a = 0; a < 2; ++a)
#pragma unroll
    for (int b = 0; b < 4; ++b) acc[a][b] = (f32x4){0.f, 0.f, 0.f, 0.f};
  const int mrow = lane & 15, kseg = (lane >> 4) * 8;
  // async staging (wave-uniform base + lane*16B, contiguous):
  const int srowX = wave * 16 + (lane >> 2);          // Xs: 64 rows, 1 issue/wave
  const int srowY = wave * 32 + (lane >> 2);          // Ys: 128 rows, 2 issues/wave
  const int scol = (lane & 3) * 8;

  for (int k0 = 0; k0 < 2048; k0 += 32) {
    __syncthreads();
    __builtin_amdgcn_global_load_lds(
        AS1C(Hf + (size_t)(row0 + srowX) * 2048 + k0 + scol),
        AS3(Xs + (wave * 16) * 32), 16, 0, 0);
#pragma unroll
    for (int q = 0; q < 2; ++q) {
      __builtin_amdgcn_global_load_lds(
          AS1C(Hf + (size_t)(col0 + srowY + q * 16) * 2048 + k0 + scol),
          AS3(Ys + (wave * 32 + q * 16) * 32), 16, 0, 0);
    }
    __syncthreads();
    half8 af[2], bf[4];
#pragma unroll
    for (int t = 0; t < 2; ++t)
      af[t] = *(const half8*)(Xs + (m0 + t * 16 + mrow) * 32 + kseg);
#pragma unroll
    for (int t = 0; t < 4; ++t)
      bf[t] = *(const half8*)(Ys + (n0 + t * 16 + mrow) * 32 + kseg);
#pragma unroll
    for (int mt = 0; mt < 2; ++mt)
#pragma unroll
      for (int nt = 0; nt < 4; ++nt)
        acc[mt][nt] = __builtin_amdgcn_mfma_f32_16x16x32_f16(af[mt], bf[nt], acc[mt][nt], 0, 0, 0);
  }
  // C/D layout: col = lane&15, row = (lane>>4)*4 + reg   [m89-verified, dtype-indep]
  const int crow = (lane >> 4) * 4, ccol = lane & 15;
  const float invn = 1.0f / 2048.0f;
#pragma unroll
  for (int mt = 0; mt < 2; ++mt)
#pragma unroll
    for (int nt = 0; nt < 4; ++nt) {
      const int gi0 = row0 + m0 + mt * 16 + crow;
      const int gj = col0 + n0 + nt * 16 + ccol;
      size_t base = (size_t)gi0 * 2048 + gj;
#pragma unroll
      for (int r = 0; r < 4; ++r)
        A[base + (size_t)r * 2048] = acc[mt][nt][r] * invn + ((gi0 + r == gj) ? 1.0f : 0.0f);
    }
}

// ---- 4. fill fixed-stride bins: slot = atomic alloc in cnt[r] (no count/scan) ----
__global__ __launch_bounds__(256) void fill_kernel(const float* __restrict__ pred,
                                                   const float* __restrict__ scal,
                                                   const int* __restrict__ rows,
                                                   const int* __restrict__ cols,
                                                   unsigned* __restrict__ cnt,
                                                   int* __restrict__ bcol,
                                                   float* __restrict__ bval) {
  int k = blockIdx.x * 256 + threadIdx.x;
  int r = rows[k];
  unsigned pos = atomicAdd(&cnt[r], 1u);
  if (pos < BINCAP) {                       // Poisson(16) tail guard, ~never taken
    bcol[r * BINCAP + pos] = cols[k];
    bval[r * BINCAP + pos] = pred[k] * scal[k];
  }
}

// ---- 4d. F[r,:] = sum_e val_e * A[col_e,:]  (float4, block r owns row r) ----
__global__ __launch_bounds__(256) void gatherF_kernel(const unsigned* __restrict__ cnt,
                                                      const int* __restrict__ bcol,
                                                      const float* __restrict__ bval,
                                                      const float* __restrict__ A,
                                                      float* __restrict__ F) {
  const int r = blockIdx.x, tid = threadIdx.x;
  float4 a0 = {0.f, 0.f, 0.f, 0.f}, a1 = {0.f, 0.f, 0.f, 0.f};
  const unsigned ne = min(cnt[r], (unsigned)BINCAP);
  for (unsigned e = 0; e < ne; ++e) {
    const float v = bval[r * BINCAP + e];
    const float4* Ar = (const float4*)(A + (size_t)bcol[r * BINCAP + e] * 2048);
    float4 x0 = Ar[tid], x1 = Ar[tid + 256];
    a0.x += v * x0.x; a0.y += v * x0.y; a0.z += v * x0.z; a0.w += v * x0.w;
    a1.x += v * x1.x; a1.y += v * x1.y; a1.z += v * x1.z; a1.w += v * x1.w;
  }
  float4* Fr = (float4*)(F + (size_t)r * 2048);
  Fr[tid] = a0;
  Fr[tid + 256] = a1;
}

// ---- 4e. M[r,:] += sum_e val_e * Ft[col_e,:]  (float4) ----
__global__ __launch_bounds__(256) void gatherM_kernel(const unsigned* __restrict__ cnt,
                                                      const int* __restrict__ bcol,
                                                      const float* __restrict__ bval,
                                                      const float* __restrict__ Ft,
                                                      float* __restrict__ M) {
  const int r = blockIdx.x, tid = threadIdx.x;
  float4 a0 = {0.f, 0.f, 0.f, 0.f}, a1 = {0.f, 0.f, 0.f, 0.f};
  const unsigned ne = min(cnt[r], (unsigned)BINCAP);
  for (unsigned e = 0; e < ne; ++e) {
    const float v = bval[r * BINCAP + e];
    const float4* Fr = (const float4*)(Ft + (size_t)bcol[r * BINCAP + e] * 2048);
    float4 x0 = Fr[tid], x1 = Fr[tid + 256];
    a0.x += v * x0.x; a0.y += v * x0.y; a0.z += v * x0.z; a0.w += v * x0.w;
    a1.x += v * x1.x; a1.y += v * x1.y; a1.z += v * x1.z; a1.w += v * x1.w;
  }
  float4* Mr = (float4*)(M + (size_t)r * 2048);
  float4 m0 = Mr[tid], m1 = Mr[tid + 256];
  m0.x += a0.x; m0.y += a0.y; m0.z += a0.z; m0.w += a0.w;
  m1.x += a1.x; m1.y += a1.y; m1.z += a1.z; m1.w += a1.w;
  Mr[tid] = m0;
  Mr[tid + 256] = m1;
}

// ---- 5. M += F + F^T;  Ft = F^T ----
__global__ __launch_bounds__(256) void addsym_kernel(const float* __restrict__ F,
                                                     float* __restrict__ M,
                                                     float* __restrict__ Ft) {
  __shared__ float T2[32][33];
  const int bi = blockIdx.x, bj = blockIdx.y;
  const int c = threadIdx.x & 31, r0 = threadIdx.x >> 5;
#pragma unroll
  for (int it = 0; it < 4; ++it) {
    int r = r0 + it * 8;
    T2[r][c] = F[(size_t)(bj * 32 + r) * 2048 + bi * 32 + c];
  }
  __syncthreads();
#pragma unroll
  for (int it = 0; it < 4; ++it) {
    int r = r0 + it * 8;
    size_t idx = (size_t)(bi * 32 + r) * 2048 + bj * 32 + c;
    float ft = T2[c][r];
    M[idx] += F[idx] + ft;
    Ft[idx] = ft;
  }
}

// ---- deterministic block-wide sum: identical bitwise result in every block ----
__device__ __forceinline__ float block_sum(float v, float* red) {
#pragma unroll
  for (int off = 32; off; off >>= 1) v += __shfl_down(v, off);
  if ((threadIdx.x & 63) == 0) red[threadIdx.x >> 6] = v;
  __syncthreads();
  float r = red[0] + red[1] + red[2] + red[3];
  __syncthreads();
  return r;
}

// ---- 6. Lanczos with epoch-tagged Z: NO flags, NO separate barrier ----
// LAUNCHED AS A PLAIN KERNEL (R14 measurement: one hipLaunchCooperativeKernel
// costs ~85 us of validation overhead even under graph replay). Co-residency
// holds by construction: 256 blocks = 1/CU (256 CUs), 4 waves/block << 32
// waves/CU, 16.9 KB LDS << 160 KB, 60 VGPR -> all blocks resident at t=0,
// so the spin-wait protocol cannot deadlock.
// RULE 1 (R1/R6): every cross-block datum moves via agent-scope (sc1) atomic
// loads AND stores. Each Z entry is a 64-bit word {epoch j | float bits};
// one polled 8B sc1 load is both barrier and data.
// RULE 2 (R1/R6/R8, 3/3): beta^2 = ||z - alpha v||^2 DIRECT form only —
// the ||z||^2 - alpha^2 identity feeds normalization error back with gain
// ~alpha^2/beta^2 (~10x/iter) -> lambda_min collapse.
// Ping-pong: a block writes Z_{j+1} only after reading ALL of Z_j, whose
// rows prove every block consumed Z_{j-1} => clobber-safe, skew <= 1 iter.
// Poison epochs (0xAA..) fail the equality check => safe under re-poison.
__global__ __launch_bounds__(256) void lanczos_kernel(const float* __restrict__ M,
                                                      unsigned long long* __restrict__ Z0,
                                                      unsigned long long* __restrict__ Z1,
                                                      float* __restrict__ out) {
  const int tid = threadIdx.x, b = blockIdx.x;
  const int wave = tid >> 6, lane = tid & 63;
  __shared__ __align__(16) float VA[2048];
  __shared__ __align__(16) float VB[2048];
  __shared__ float red[4];
  __shared__ float al[LK + 2], b2[LK + 2];
  __shared__ float bnds[2], res[2];

  // block-redundant init: v1 = hash / ||hash||  (identical in every block), v0 = 0
  float pv[8];
  float part = 0.f;
#pragma unroll
  for (int t = 0; t < 8; ++t) {
    int i = t * 256 + tid;
    unsigned u = (unsigned)i * 2654435761u;
    u ^= u >> 16; u *= 2246822519u; u ^= u >> 13;
    float rv = (float)(u >> 8) * (2.f / 16777216.f) - 1.f;
    pv[t] = rv;
    part += rv * rv;
  }
  float nrm = block_sum(part, red);
  float innm = rsqrtf(nrm);
#pragma unroll
  for (int t = 0; t < 8; ++t) {
    int i = t * 256 + tid;
    VA[i] = pv[t] * innm;
    VB[i] = 0.f;
  }
  __syncthreads();

  float* Vcur = VA;
  float* Vprev = VB;
  float beta_prev = 0.f;

  for (int j = 1; j <= LK; ++j) {
    unsigned long long* Z = (j & 1) ? Z0 : Z1;
    // --- this block's 8 rows of z = M v_j - beta_{j-1} v_{j-1} ---
#pragma unroll
    for (int rr = 0; rr < 2; ++rr) {
      const int r = b * 8 + wave * 2 + rr;
      const float4* Mr = (const float4*)(M + (size_t)r * 2048);
      float s = 0.f;
#pragma unroll
      for (int t = 0; t < 8; ++t) {
        int idx = t * 64 + lane;
        float4 m4 = Mr[idx];
        float4 v4 = ((const float4*)Vcur)[idx];
        s += m4.x * v4.x + m4.y * v4.y + m4.z * v4.z + m4.w * v4.w;
      }
#pragma unroll
      for (int off = 32; off; off >>= 1) s += __shfl_down(s, off);
      if (lane == 0) {
        float zv = s - beta_prev * Vprev[r];
        unsigned long long pk = ((unsigned long long)(unsigned)j << 32) |
                                (unsigned long long)(unsigned)__float_as_uint(zv);
        __hip_atomic_store(&Z[r], pk, __ATOMIC_RELAXED, AGENT);
      }
    }

    // --- poll own 8 Z words until their epoch == j, then consume payload ---
    unsigned long long w8[8];
    for (;;) {
      bool ok = true;
#pragma unroll
      for (int t = 0; t < 8; ++t) {
        w8[t] = __hip_atomic_load(&Z[t * 256 + tid], __ATOMIC_RELAXED, AGENT);
        ok &= ((unsigned)(w8[t] >> 32) == (unsigned)j);
      }
      if (ok) break;
    }
    // --- redundant deterministic scalars, DIRECT beta form (Rule 2) ---
    float za[8], va[8];
    float pa = 0.f;
#pragma unroll
    for (int t = 0; t < 8; ++t) {
      za[t] = __uint_as_float((unsigned)w8[t]);
      va[t] = Vcur[t * 256 + tid];
      pa += za[t] * va[t];
    }
    float alpha = block_sum(pa, red);
    float pb = 0.f;
#pragma unroll
    for (int t = 0; t < 8; ++t) {
      float rsd = za[t] - alpha * va[t];
      pb += rsd * rsd;
    }
    float beta2 = block_sum(pb, red);
    float beta = sqrtf(fmaxf(beta2, 1e-30f));
    float invb = 1.f / beta;
    if (tid == 0) { al[j] = alpha; b2[j] = beta2; }
    // rotate: overwrite Vprev storage (v_{j-1} dead) with v_{j+1}
#pragma unroll
    for (int t = 0; t < 8; ++t) {
      int i = t * 256 + tid;
      Vprev[i] = (za[t] - alpha * va[t]) * invb;
    }
    float* tmp = Vprev; Vprev = Vcur; Vcur = tmp;
    beta_prev = beta;
    __syncthreads();
  }

  // ---- extreme eigenvalues of T via Sturm bisection (block 0) ----
  if (b == 0) {
    if (tid == 0) {                                  // Gershgorin bounds on T
      float lo = 1e30f, hi = -1e30f;
      for (int i = 1; i <= LK; ++i) {
        float bl = (i > 1) ? sqrtf(b2[i - 1]) : 0.f;
        float br = (i < LK) ? sqrtf(b2[i]) : 0.f;
        lo = fminf(lo, al[i] - bl - br);
        hi = fmaxf(hi, al[i] + bl + br);
      }
      bnds[0] = lo; bnds[1] = hi;
    }
    __syncthreads();
    if (wave < 2) {                 // wave 0 -> lambda_min, wave 1 -> lambda_max
      const int tcount = (wave == 0) ? 1 : LK;
      float lo = bnds[0], hi = bnds[1];
      for (int round = 0; round < 4; ++round) {
        float x = lo + (hi - lo) * (float)(lane + 1) * (1.f / 65.f);
        int cnt = 0;                                 // #eigs of T below x
        float d = al[1] - x;
        if (fabsf(d) < 1e-25f) d = -1e-25f;
        if (d < 0.f) cnt++;
        for (int i = 2; i <= LK; ++i) {
          d = (al[i] - x) - b2[i - 1] / d;
          if (fabsf(d) < 1e-25f) d = -1e-25f;
          if (d < 0.f) cnt++;
        }
        bool ab = (cnt >= tcount);                   // x is above the target eig
        float cand_hi = ab ? x : hi;
        float cand_lo = ab ? lo : x;
#pragma unroll
        for (int off = 32; off; off >>= 1) {
          cand_hi = fminf(cand_hi, __shfl_down(cand_hi, off));
          cand_lo = fmaxf(cand_lo, __shfl_down(cand_lo, off));
        }
        cand_hi = __shfl(cand_hi, 0);
        cand_lo = __shfl(cand_lo, 0);
        hi = cand_hi;
        lo = fminf(cand_lo, hi);
      }
      if (lane == 0) res[wave] = 0.5f * (lo + hi);
    }
    __syncthreads();
    if (tid == 0) {
      float lmin = fmaxf(res[0], 1e-12f);
      float lmax = fmaxf(res[1], 1e-12f);
      out[0] = logf(lmax) - logf(lmin);
    }
  }
}

extern "C" void kernel_launch(void* const* d_in, const int* in_sizes, int n_in,
                              void* d_out, int out_size, void* d_ws, size_t ws_size,
                              hipStream_t stream) {
  const float* pred = (const float*)d_in[0];
  const float* scal = (const float*)d_in[1];
  const float* W    = (const float*)d_in[2];
  const int*   rows = (const int*)d_in[3];
  const int*   cols = (const int*)d_in[4];
  float* out = (float*)d_out;

  // workspace layout (peak ~49.1 MB):
  //  [0,16MB)  : Hf fp16 (8MB) during GEMM, then Ft (16MB)
  //  [16,32MB) : F
  //  [32,48MB) : A (written directly by GEMM), updated in place into M
  //  [48MB,..) : cnt, fixed-stride bins, epoch-tagged Z ping-pong
  char* ws = (char*)d_ws;
  const size_t MB = 1024 * 1024;
  unsigned short* Hf = (unsigned short*)(ws);
  float* F  = (float*)(ws + 16 * MB);
  float* A  = (float*)(ws + 32 * MB);
  float* Ft = (float*)(ws);             // reuses Hf (dead after gemm)
  char* ctrl = ws + 48 * MB;
  unsigned* cnt  = (unsigned*)(ctrl);                    //  8 KB (zeroed by convert)
  int*      bcol = (int*)(ctrl + 8192);                  //  512 KB (2048 x 64)
  float*    bval = (float*)(ctrl + 8192 + 524288);       //  512 KB
  unsigned long long* Z0 = (unsigned long long*)(ctrl + 8192 + 1048576);         // 16 KB
  unsigned long long* Z1 = (unsigned long long*)(ctrl + 8192 + 1048576 + 16384); // 16 KB

  convert_kernel<<<4096, 256, 0, stream>>>(W, Hf, cnt);
  gemm_f16_kernel<<<512, 256, 0, stream>>>(Hf, A);       // A = W W^T/N + I directly

  fill_kernel<<<NNZ / 256, 256, 0, stream>>>(pred, scal, rows, cols, cnt, bcol, bval);

  gatherF_kernel<<<2048, 256, 0, stream>>>(cnt, bcol, bval, A, F);   // F = S*A
  addsym_kernel<<<dim3(64, 64), 256, 0, stream>>>(F, A, Ft);         // M = A+F+F^T; Ft=F^T
  gatherM_kernel<<<2048, 256, 0, stream>>>(cnt, bcol, bval, Ft, A);  // M += S*F^T

  // plain launch — co-residency by construction (256 blocks, 1/CU); saves ~85 us
  lanczos_kernel<<<NB, 256, 0, stream>>>(A, Z0, Z1, out);
}

// Round 17
// 322.983 us; speedup vs baseline: 1.9742x; 1.0007x over previous
//
#include <hip/hip_runtime.h>

// Problem constants (fixed by the reference)
#define N2 2048
#define NNZ 32768
#define LK 22          // FROZEN: absmax 0.0234 of 0.037 threshold (3 of ~4.7 bf16 ulps)
#define NB 256         // lanczos grid blocks = 1/CU -> co-resident by construction
#define BINCAP 64      // slots per row bin (Poisson(16) tail ~1e-15)

typedef __attribute__((ext_vector_type(8))) _Float16 half8;
typedef __attribute__((ext_vector_type(4))) float f32x4;

#define AGENT __HIP_MEMORY_SCOPE_AGENT
#define AS1C(p) ((const __attribute__((address_space(1))) unsigned int*)(p))
#define AS3(p)  ((__attribute__((address_space(3))) unsigned int*)(p))

__device__ __forceinline__ unsigned short f2h(float f) {
  _Float16 h = (_Float16)f;                   // fp16 RNE; |W| < ~5.5, in range
  return *(unsigned short*)&h;
}

// ---- 1. W (fp32) -> fp16  (+ zero cnt for the binning pass) ----
__global__ __launch_bounds__(256) void convert_kernel(const float* __restrict__ W,
                                                      unsigned short* __restrict__ Hf,
                                                      unsigned* __restrict__ cnt) {
  if (blockIdx.x < 8) cnt[blockIdx.x * 256 + threadIdx.x] = 0;
  int i4 = blockIdx.x * 256 + threadIdx.x;          // grid 4096 -> 1048576 float4s
  float4 w = ((const float4*)W)[i4];
  ushort4 h;
  h.x = f2h(w.x); h.y = f2h(w.y); h.z = f2h(w.z); h.w = f2h(w.w);
  ((ushort4*)Hf)[i4] = h;
}

// ---- 2. A = Hf*Hf^T/N + I  (single fp16 pass; exactly symmetric by construction:
//         (W+E)(W+E)^T — no symmetrization pass needed; eig shift <= 2|W||E|/N ~ 0.0024)
//         64x128 tile, 512 blocks = 2/CU at N=2048; epilogue applies /N + I ----
__global__ __launch_bounds__(256) void gemm_f16_kernel(const unsigned short* __restrict__ Hf,
                                                       float* __restrict__ A) {
  __shared__ unsigned short Xs[64 * 32];
  __shared__ unsigned short Ys[128 * 32];
  const int tid = threadIdx.x;
  const int wave = tid >> 6, lane = tid & 63;
  const int bi = blockIdx.x >> 4, bj = blockIdx.x & 15;   // 32 x 16 tiles
  const int row0 = bi * 64, col0 = bj * 128;
  const int m0 = (wave & 1) * 32, n0 = (wave >> 1) * 64;
  f32x4 acc[2][4];
#pragma unroll
  for (int a = 0; a < 2; ++a)
#pragma unroll
    for (int b = 0; b < 4; ++b) acc[a][b] = (f32x4){0.f, 0.f, 0.f, 0.f};
  const int mrow = lane & 15, kseg = (lane >> 4) * 8;
  // async staging (wave-uniform base + lane*16B, contiguous):
  const int srowX = wave * 16 + (lane >> 2);          // Xs: 64 rows, 1 issue/wave
  const int srowY = wave * 32 + (lane >> 2);          // Ys: 128 rows, 2 issues/wave
  const int scol = (lane & 3) * 8;

  for (int k0 = 0; k0 < 2048; k0 += 32) {
    __syncthreads();
    __builtin_amdgcn_global_load_lds(
        AS1C(Hf + (size_t)(row0 + srowX) * 2048 + k0 + scol),
        AS3(Xs + (wave * 16) * 32), 16, 0, 0);
#pragma unroll
    for (int q = 0; q < 2; ++q) {
      __builtin_amdgcn_global_load_lds(
          AS1C(Hf + (size_t)(col0 + srowY + q * 16) * 2048 + k0 + scol),
          AS3(Ys + (wave * 32 + q * 16) * 32), 16, 0, 0);
    }
    __syncthreads();
    half8 af[2], bf[4];
#pragma unroll
    for (int t = 0; t < 2; ++t)
      af[t] = *(const half8*)(Xs + (m0 + t * 16 + mrow) * 32 + kseg);
#pragma unroll
    for (int t = 0; t < 4; ++t)
      bf[t] = *(const half8*)(Ys + (n0 + t * 16 + mrow) * 32 + kseg);
#pragma unroll
    for (int mt = 0; mt < 2; ++mt)
#pragma unroll
      for (int nt = 0; nt < 4; ++nt)
        acc[mt][nt] = __builtin_amdgcn_mfma_f32_16x16x32_f16(af[mt], bf[nt], acc[mt][nt], 0, 0, 0);
  }
  // C/D layout: col = lane&15, row = (lane>>4)*4 + reg   [m89-verified, dtype-indep]
  const int crow = (lane >> 4) * 4, ccol = lane & 15;
  const float invn = 1.0f / 2048.0f;
#pragma unroll
  for (int mt = 0; mt < 2; ++mt)
#pragma unroll
    for (int nt = 0; nt < 4; ++nt) {
      const int gi0 = row0 + m0 + mt * 16 + crow;
      const int gj = col0 + n0 + nt * 16 + ccol;
      size_t base = (size_t)gi0 * 2048 + gj;
#pragma unroll
      for (int r = 0; r < 4; ++r)
        A[base + (size_t)r * 2048] = acc[mt][nt][r] * invn + ((gi0 + r == gj) ? 1.0f : 0.0f);
    }
}

// ---- 4. fill fixed-stride bins: slot = atomic alloc in cnt[r] (no count/scan) ----
__global__ __launch_bounds__(256) void fill_kernel(const float* __restrict__ pred,
                                                   const float* __restrict__ scal,
                                                   const int* __restrict__ rows,
                                                   const int* __restrict__ cols,
                                                   unsigned* __restrict__ cnt,
                                                   int* __restrict__ bcol,
                                                   float* __restrict__ bval) {
  int k = blockIdx.x * 256 + threadIdx.x;
  int r = rows[k];
  unsigned pos = atomicAdd(&cnt[r], 1u);
  if (pos < BINCAP) {                       // Poisson(16) tail guard, ~never taken
    bcol[r * BINCAP + pos] = cols[k];
    bval[r * BINCAP + pos] = pred[k] * scal[k];
  }
}

// ---- 4d. F[r,:] = sum_e val_e * A[col_e,:]  (float4, block r owns row r) ----
__global__ __launch_bounds__(256) void gatherF_kernel(const unsigned* __restrict__ cnt,
                                                      const int* __restrict__ bcol,
                                                      const float* __restrict__ bval,
                                                      const float* __restrict__ A,
                                                      float* __restrict__ F) {
  const int r = blockIdx.x, tid = threadIdx.x;
  float4 a0 = {0.f, 0.f, 0.f, 0.f}, a1 = {0.f, 0.f, 0.f, 0.f};
  const unsigned ne = min(cnt[r], (unsigned)BINCAP);
  for (unsigned e = 0; e < ne; ++e) {
    const float v = bval[r * BINCAP + e];
    const float4* Ar = (const float4*)(A + (size_t)bcol[r * BINCAP + e] * 2048);
    float4 x0 = Ar[tid], x1 = Ar[tid + 256];
    a0.x += v * x0.x; a0.y += v * x0.y; a0.z += v * x0.z; a0.w += v * x0.w;
    a1.x += v * x1.x; a1.y += v * x1.y; a1.z += v * x1.z; a1.w += v * x1.w;
  }
  float4* Fr = (float4*)(F + (size_t)r * 2048);
  Fr[tid] = a0;
  Fr[tid + 256] = a1;
}

// ---- 4e. M[r,:] += sum_e val_e * Ft[col_e,:]  (float4) ----
__global__ __launch_bounds__(256) void gatherM_kernel(const unsigned* __restrict__ cnt,
                                                      const int* __restrict__ bcol,
                                                      const float* __restrict__ bval,
                                                      const float* __restrict__ Ft,
                                                      float* __restrict__ M) {
  const int r = blockIdx.x, tid = threadIdx.x;
  float4 a0 = {0.f, 0.f, 0.f, 0.f}, a1 = {0.f, 0.f, 0.f, 0.f};
  const unsigned ne = min(cnt[r], (unsigned)BINCAP);
  for (unsigned e = 0; e < ne; ++e) {
    const float v = bval[r * BINCAP + e];
    const float4* Fr = (const float4*)(Ft + (size_t)bcol[r * BINCAP + e] * 2048);
    float4 x0 = Fr[tid], x1 = Fr[tid + 256];
    a0.x += v * x0.x; a0.y += v * x0.y; a0.z += v * x0.z; a0.w += v * x0.w;
    a1.x += v * x1.x; a1.y += v * x1.y; a1.z += v * x1.z; a1.w += v * x1.w;
  }
  float4* Mr = (float4*)(M + (size_t)r * 2048);
  float4 m0 = Mr[tid], m1 = Mr[tid + 256];
  m0.x += a0.x; m0.y += a0.y; m0.z += a0.z; m0.w += a0.w;
  m1.x += a1.x; m1.y += a1.y; m1.z += a1.z; m1.w += a1.w;
  Mr[tid] = m0;
  Mr[tid + 256] = m1;
}

// ---- 5. M += F + F^T;  Ft = F^T ----
__global__ __launch_bounds__(256) void addsym_kernel(const float* __restrict__ F,
                                                     float* __restrict__ M,
                                                     float* __restrict__ Ft) {
  __shared__ float T2[32][33];
  const int bi = blockIdx.x, bj = blockIdx.y;
  const int c = threadIdx.x & 31, r0 = threadIdx.x >> 5;
#pragma unroll
  for (int it = 0; it < 4; ++it) {
    int r = r0 + it * 8;
    T2[r][c] = F[(size_t)(bj * 32 + r) * 2048 + bi * 32 + c];
  }
  __syncthreads();
#pragma unroll
  for (int it = 0; it < 4; ++it) {
    int r = r0 + it * 8;
    size_t idx = (size_t)(bi * 32 + r) * 2048 + bj * 32 + c;
    float ft = T2[c][r];
    M[idx] += F[idx] + ft;
    Ft[idx] = ft;
  }
}

// ---- deterministic block-wide sum: identical bitwise result in every block ----
__device__ __forceinline__ float block_sum(float v, float* red) {
#pragma unroll
  for (int off = 32; off; off >>= 1) v += __shfl_down(v, off);
  if ((threadIdx.x & 63) == 0) red[threadIdx.x >> 6] = v;
  __syncthreads();
  float r = red[0] + red[1] + red[2] + red[3];
  __syncthreads();
  return r;
}

// ---- 6. Lanczos with epoch-tagged Z: NO flags, NO separate barrier ----
// LAUNCHED AS A PLAIN KERNEL (R14 measurement: one hipLaunchCooperativeKernel
// costs extra validation overhead even under graph replay). Co-residency
// holds by construction: 256 blocks = 1/CU (256 CUs), 4 waves/block << 32
// waves/CU, 16.9 KB LDS << 160 KB, 60 VGPR -> all blocks resident at t=0,
// so the spin-wait protocol cannot deadlock.
// RULE 1 (R1/R6): every cross-block datum moves via agent-scope (sc1) atomic
// loads AND stores. Each Z entry is a 64-bit word {epoch j | float bits};
// one polled 8B sc1 load is both barrier and data.
// RULE 2 (R1/R6/R8, 3/3): beta^2 = ||z - alpha v||^2 DIRECT form only —
// the ||z||^2 - alpha^2 identity feeds normalization error back with gain
// ~alpha^2/beta^2 (~10x/iter) -> lambda_min collapse.
// RULE 3 (R16 failure): do NOT reuse a fixed-address cross-block staging
// buffer inside the unfenced loop with "cache-bypass" loads — sc0 does not
// reliably bypass L1 on gfx950; stale reads corrupt T from iter 2 onward.
// Ping-pong: a block writes Z_{j+1} only after reading ALL of Z_j, whose
// rows prove every block consumed Z_{j-1} => clobber-safe, skew <= 1 iter.
// Poison epochs (0xAA..) fail the equality check => safe under re-poison.
__global__ __launch_bounds__(256) void lanczos_kernel(const float* __restrict__ M,
                                                      unsigned long long* __restrict__ Z0,
                                                      unsigned long long* __restrict__ Z1,
                                                      float* __restrict__ out) {
  const int tid = threadIdx.x, b = blockIdx.x;
  const int wave = tid >> 6, lane = tid & 63;
  __shared__ __align__(16) float VA[2048];
  __shared__ __align__(16) float VB[2048];
  __shared__ float red[4];
  __shared__ float al[LK + 2], b2[LK + 2];
  __shared__ float bnds[2], res[2];

  // block-redundant init: v1 = hash / ||hash||  (identical in every block), v0 = 0
  float pv[8];
  float part = 0.f;
#pragma unroll
  for (int t = 0; t < 8; ++t) {
    int i = t * 256 + tid;
    unsigned u = (unsigned)i * 2654435761u;
    u ^= u >> 16; u *= 2246822519u; u ^= u >> 13;
    float rv = (float)(u >> 8) * (2.f / 16777216.f) - 1.f;
    pv[t] = rv;
    part += rv * rv;
  }
  float nrm = block_sum(part, red);
  float innm = rsqrtf(nrm);
#pragma unroll
  for (int t = 0; t < 8; ++t) {
    int i = t * 256 + tid;
    VA[i] = pv[t] * innm;
    VB[i] = 0.f;
  }
  __syncthreads();

  float* Vcur = VA;
  float* Vprev = VB;
  float beta_prev = 0.f;

  for (int j = 1; j <= LK; ++j) {
    unsigned long long* Z = (j & 1) ? Z0 : Z1;
    // --- this block's 8 rows of z = M v_j - beta_{j-1} v_{j-1} ---
#pragma unroll
    for (int rr = 0; rr < 2; ++rr) {
      const int r = b * 8 + wave * 2 + rr;
      const float4* Mr = (const float4*)(M + (size_t)r * 2048);
      float s = 0.f;
#pragma unroll
      for (int t = 0; t < 8; ++t) {
        int idx = t * 64 + lane;
        float4 m4 = Mr[idx];
        float4 v4 = ((const float4*)Vcur)[idx];
        s += m4.x * v4.x + m4.y * v4.y + m4.z * v4.z + m4.w * v4.w;
      }
#pragma unroll
      for (int off = 32; off; off >>= 1) s += __shfl_down(s, off);
      if (lane == 0) {
        float zv = s - beta_prev * Vprev[r];
        unsigned long long pk = ((unsigned long long)(unsigned)j << 32) |
                                (unsigned long long)(unsigned)__float_as_uint(zv);
        __hip_atomic_store(&Z[r], pk, __ATOMIC_RELAXED, AGENT);
      }
    }

    // --- poll own 8 Z words until their epoch == j, then consume payload ---
    unsigned long long w8[8];
    for (;;) {
      bool ok = true;
#pragma unroll
      for (int t = 0; t < 8; ++t) {
        w8[t] = __hip_atomic_load(&Z[t * 256 + tid], __ATOMIC_RELAXED, AGENT);
        ok &= ((unsigned)(w8[t] >> 32) == (unsigned)j);
      }
      if (ok) break;
    }
    // --- redundant deterministic scalars, DIRECT beta form (Rule 2) ---
    float za[8], va[8];
    float pa = 0.f;
#pragma unroll
    for (int t = 0; t < 8; ++t) {
      za[t] = __uint_as_float((unsigned)w8[t]);
      va[t] = Vcur[t * 256 + tid];
      pa += za[t] * va[t];
    }
    float alpha = block_sum(pa, red);
    float pb = 0.f;
#pragma unroll
    for (int t = 0; t < 8; ++t) {
      float rsd = za[t] - alpha * va[t];
      pb += rsd * rsd;
    }
    float beta2 = block_sum(pb, red);
    float beta = sqrtf(fmaxf(beta2, 1e-30f));
    float invb = 1.f / beta;
    if (tid == 0) { al[j] = alpha; b2[j] = beta2; }
    // rotate: overwrite Vprev storage (v_{j-1} dead) with v_{j+1}
#pragma unroll
    for (int t = 0; t < 8; ++t) {
      int i = t * 256 + tid;
      Vprev[i] = (za[t] - alpha * va[t]) * invb;
    }
    float* tmp = Vprev; Vprev = Vcur; Vcur = tmp;
    beta_prev = beta;
    __syncthreads();
  }

  // ---- extreme eigenvalues of T via Sturm bisection (block 0) ----
  if (b == 0) {
    if (tid == 0) {                                  // Gershgorin bounds on T
      float lo = 1e30f, hi = -1e30f;
      for (int i = 1; i <= LK; ++i) {
        float bl = (i > 1) ? sqrtf(b2[i - 1]) : 0.f;
        float br = (i < LK) ? sqrtf(b2[i]) : 0.f;
        lo = fminf(lo, al[i] - bl - br);
        hi = fmaxf(hi, al[i] + bl + br);
      }
      bnds[0] = lo; bnds[1] = hi;
    }
    __syncthreads();
    if (wave < 2) {                 // wave 0 -> lambda_min, wave 1 -> lambda_max
      const int tcount = (wave == 0) ? 1 : LK;
      float lo = bnds[0], hi = bnds[1];
      for (int round = 0; round < 4; ++round) {
        float x = lo + (hi - lo) * (float)(lane + 1) * (1.f / 65.f);
        int cnt = 0;                                 // #eigs of T below x
        float d = al[1] - x;
        if (fabsf(d) < 1e-25f) d = -1e-25f;
        if (d < 0.f) cnt++;
        for (int i = 2; i <= LK; ++i) {
          d = (al[i] - x) - b2[i - 1] / d;
          if (fabsf(d) < 1e-25f) d = -1e-25f;
          if (d < 0.f) cnt++;
        }
        bool ab = (cnt >= tcount);                   // x is above the target eig
        float cand_hi = ab ? x : hi;
        float cand_lo = ab ? lo : x;
#pragma unroll
        for (int off = 32; off; off >>= 1) {
          cand_hi = fminf(cand_hi, __shfl_down(cand_hi, off));
          cand_lo = fmaxf(cand_lo, __shfl_down(cand_lo, off));
        }
        cand_hi = __shfl(cand_hi, 0);
        cand_lo = __shfl(cand_lo, 0);
        hi = cand_hi;
        lo = fminf(cand_lo, hi);
      }
      if (lane == 0) res[wave] = 0.5f * (lo + hi);
    }
    __syncthreads();
    if (tid == 0) {
      float lmin = fmaxf(res[0], 1e-12f);
      float lmax = fmaxf(res[1], 1e-12f);
      out[0] = logf(lmax) - logf(lmin);
    }
  }
}

extern "C" void kernel_launch(void* const* d_in, const int* in_sizes, int n_in,
                              void* d_out, int out_size, void* d_ws, size_t ws_size,
                              hipStream_t stream) {
  const float* pred = (const float*)d_in[0];
  const float* scal = (const float*)d_in[1];
  const float* W    = (const float*)d_in[2];
  const int*   rows = (const int*)d_in[3];
  const int*   cols = (const int*)d_in[4];
  float* out = (float*)d_out;

  // workspace layout (peak ~49.1 MB):
  //  [0,16MB)  : Hf fp16 (8MB) during GEMM, then Ft (16MB)
  //  [16,32MB) : F
  //  [32,48MB) : A (written directly by GEMM), updated in place into M
  //  [48MB,..) : cnt, fixed-stride bins, epoch-tagged Z ping-pong
  char* ws = (char*)d_ws;
  const size_t MB = 1024 * 1024;
  unsigned short* Hf = (unsigned short*)(ws);
  float* F  = (float*)(ws + 16 * MB);
  float* A  = (float*)(ws + 32 * MB);
  float* Ft = (float*)(ws);             // reuses Hf (dead after gemm)
  char* ctrl = ws + 48 * MB;
  unsigned* cnt  = (unsigned*)(ctrl);                    //  8 KB (zeroed by convert)
  int*      bcol = (int*)(ctrl + 8192);                  //  512 KB (2048 x 64)
  float*    bval = (float*)(ctrl + 8192 + 524288);       //  512 KB
  unsigned long long* Z0 = (unsigned long long*)(ctrl + 8192 + 1048576);         // 16 KB
  unsigned long long* Z1 = (unsigned long long*)(ctrl + 8192 + 1048576 + 16384); // 16 KB

  convert_kernel<<<4096, 256, 0, stream>>>(W, Hf, cnt);
  gemm_f16_kernel<<<512, 256, 0, stream>>>(Hf, A);       // A = W W^T/N + I directly

  fill_kernel<<<NNZ / 256, 256, 0, stream>>>(pred, scal, rows, cols, cnt, bcol, bval);

  gatherF_kernel<<<2048, 256, 0, stream>>>(cnt, bcol, bval, A, F);   // F = S*A
  addsym_kernel<<<dim3(64, 64), 256, 0, stream>>>(F, A, Ft);         // M = A+F+F^T; Ft=F^T
  gatherM_kernel<<<2048, 256, 0, stream>>>(cnt, bcol, bval, Ft, A);  // M += S*F^T

  // plain launch — co-residency by construction (256 blocks, 1/CU)
  lanczos_kernel<<<NB, 256, 0, stream>>>(A, Z0, Z1, out);
}